// Round 1
// baseline (378.239 us; speedup 1.0000x reference)
//
#include <hip/hip_runtime.h>
#include <math.h>

#define NE 320000
#define NN 20000
#define NQ 200000

// ---------------- degree / dinv ----------------
__global__ void k_set1(float* p, int n) {
  int i = blockIdx.x * 256 + threadIdx.x;
  if (i < n) p[i] = 1.0f;
}

__global__ void k_degedges(const int* __restrict__ ei, float* deg) {
  int e = blockIdx.x * 256 + threadIdx.x;
  if (e < NE) atomicAdd(&deg[ei[NE + e]], 1.0f);
}

__global__ void k_dinv(float* deg, int n) {
  int i = blockIdx.x * 256 + threadIdx.x;
  if (i < n) deg[i] = rsqrtf(fmaxf(deg[i], 1.0f));
}

// ---------------- skinny GEMM: Y(MxN) = X(MxK) @ W(KxN), W in LDS ----------------
template<int K, int N>
__global__ __launch_bounds__(256) void k_skinny(const float* __restrict__ X,
                                                const float* __restrict__ W,
                                                float* __restrict__ Y, int M) {
  constexpr int ROWS = 256 / N;
  __shared__ float Wl[K * N];
  for (int t = threadIdx.x; t < K * N; t += 256) Wl[t] = W[t];
  __syncthreads();
  int row = blockIdx.x * ROWS + threadIdx.x / N;
  int col = threadIdx.x % N;
  if (row >= M) return;
  const float* xr = X + (size_t)row * K;
  float acc = 0.0f;
#pragma unroll 16
  for (int k = 0; k < K; k++) acc = fmaf(xr[k], Wl[k * N + col], acc);
  Y[(size_t)row * N + col] = acc;
}

// no-LDS variant (big K*N): W streamed from cache
template<int K, int N>
__global__ __launch_bounds__(256) void k_skinny_g(const float* __restrict__ X,
                                                  const float* __restrict__ W,
                                                  float* __restrict__ Y, int M) {
  constexpr int ROWS = 256 / N;
  int row = blockIdx.x * ROWS + threadIdx.x / N;
  int col = threadIdx.x % N;
  if (row >= M) return;
  const float* xr = X + (size_t)row * K;
  float acc = 0.0f;
  for (int k = 0; k < K; k++) acc = fmaf(xr[k], __ldg(&W[k * N + col]), acc);
  Y[(size_t)row * N + col] = acc;
}

// ---------------- message passing: acc[dst] += h[src] * dinv[src]*dinv[dst] ----------------
template<int C>
__global__ __launch_bounds__(256) void k_mp(const int* __restrict__ ei,
                                            const float* __restrict__ h,
                                            const float* __restrict__ dinv,
                                            float* acc) {
  int lane = threadIdx.x % C;
  int le = threadIdx.x / C;
  int e = blockIdx.x * (256 / C) + le;
  if (e >= NE) return;
  int s = ei[e], d = ei[NE + e];
  float w = dinv[s] * dinv[d];
  atomicAdd(&acc[(size_t)d * C + lane], h[(size_t)s * C + lane] * w);
}

// finalize: h = relu(acc + h*dinv^2 + b)   (in-place on h)
template<int C>
__global__ void k_fin(float* __restrict__ h, const float* __restrict__ acc,
                      const float* __restrict__ dinv, const float* __restrict__ b) {
  int idx = blockIdx.x * 256 + threadIdx.x;
  if (idx >= NN * C) return;
  int i = idx / C, c = idx % C;
  float di = dinv[i];
  float v = acc[idx] + h[idx] * di * di + b[c];
  h[idx] = fmaxf(v, 0.0f);
}

// ---------------- 512x512x512 f32 GEMM (NN), 64x64 tile, 4x4 microtile ----------------
__global__ __launch_bounds__(256) void k_gemm512(const float* __restrict__ A,
                                                 const float* __restrict__ B,
                                                 float* __restrict__ C) {
  __shared__ float As[16][68]; // As[k][row], 68-pad -> rows 16B aligned
  __shared__ float Bs[16][68]; // Bs[k][col]
  int tid = threadIdx.x;
  int tx = tid & 15, ty = tid >> 4;
  int brow = (blockIdx.x >> 3) * 64;
  int bcol = (blockIdx.x & 7) * 64;
  float c[4][4] = {};
  for (int k0 = 0; k0 < 512; k0 += 16) {
#pragma unroll
    for (int t = 0; t < 4; t++) {
      int idx = tid * 4 + t;
      int r = idx >> 4, cc = idx & 15;       // A tile: 64 rows x 16 k
      As[cc][r] = A[(size_t)(brow + r) * 512 + k0 + cc];
      int r2 = idx >> 6, c2 = idx & 63;      // B tile: 16 k x 64 cols
      Bs[r2][c2] = B[(size_t)(k0 + r2) * 512 + bcol + c2];
    }
    __syncthreads();
#pragma unroll
    for (int k = 0; k < 16; k++) {
      float a0 = As[k][ty * 4 + 0], a1 = As[k][ty * 4 + 1];
      float a2 = As[k][ty * 4 + 2], a3 = As[k][ty * 4 + 3];
      float b0 = Bs[k][tx * 4 + 0], b1 = Bs[k][tx * 4 + 1];
      float b2 = Bs[k][tx * 4 + 2], b3 = Bs[k][tx * 4 + 3];
      c[0][0] = fmaf(a0, b0, c[0][0]); c[0][1] = fmaf(a0, b1, c[0][1]);
      c[0][2] = fmaf(a0, b2, c[0][2]); c[0][3] = fmaf(a0, b3, c[0][3]);
      c[1][0] = fmaf(a1, b0, c[1][0]); c[1][1] = fmaf(a1, b1, c[1][1]);
      c[1][2] = fmaf(a1, b2, c[1][2]); c[1][3] = fmaf(a1, b3, c[1][3]);
      c[2][0] = fmaf(a2, b0, c[2][0]); c[2][1] = fmaf(a2, b1, c[2][1]);
      c[2][2] = fmaf(a2, b2, c[2][2]); c[2][3] = fmaf(a2, b3, c[2][3]);
      c[3][0] = fmaf(a3, b0, c[3][0]); c[3][1] = fmaf(a3, b1, c[3][1]);
      c[3][2] = fmaf(a3, b2, c[3][2]); c[3][3] = fmaf(a3, b3, c[3][3]);
    }
    __syncthreads();
  }
#pragma unroll
  for (int i = 0; i < 4; i++)
#pragma unroll
    for (int j = 0; j < 4; j++)
      C[(size_t)(brow + ty * 4 + i) * 512 + bcol + tx * 4 + j] = c[i][j];
}

// ---------------- rel = A(512x32) @ B(512x32)^T ----------------
__global__ void k_relnt(const float* __restrict__ A, const float* __restrict__ B,
                        float* __restrict__ C) {
  int gid = blockIdx.x * 256 + threadIdx.x;
  int i = gid >> 9, j = gid & 511;
  float acc = 0.0f;
#pragma unroll
  for (int k = 0; k < 32; k++) acc = fmaf(A[i * 32 + k], B[j * 32 + k], acc);
  C[gid] = acc;
}

// ---------------- fused row-softmax(relu(S)) @ weights_sim -> M (1024x8) ----------------
__global__ __launch_bounds__(256) void k_softmaxM(const float* __restrict__ L0r,
                                                  const float* __restrict__ L1r,
                                                  const float* __restrict__ rel_,
                                                  const float* __restrict__ wsim,
                                                  float* __restrict__ M) {
  int i = blockIdx.x;   // row 0..1023
  int tid = threadIdx.x;
  float loc[4];
  float mymax = 0.0f;   // post-relu values are >= 0
#pragma unroll
  for (int t = 0; t < 4; t++) {
    int j = tid + t * 256;
    float v;
    if (i < 512) v = (j < 512) ? L0r[i * 512 + j] : rel_[i * 512 + (j - 512)];
    else {
      int r = i - 512;
      v = (j < 512) ? rel_[j * 512 + r] : L1r[r * 512 + (j - 512)];
    }
    v = fmaxf(v, 0.0f);
    loc[t] = v;
    mymax = fmaxf(mymax, v);
  }
#pragma unroll
  for (int o = 32; o > 0; o >>= 1) mymax = fmaxf(mymax, __shfl_down(mymax, o));
  __shared__ float smax[4];
  int wid = tid >> 6, lane = tid & 63;
  if (lane == 0) smax[wid] = mymax;
  __syncthreads();
  float m = fmaxf(fmaxf(smax[0], smax[1]), fmaxf(smax[2], smax[3]));

  float z = 0.0f, pm[8] = {};
#pragma unroll
  for (int t = 0; t < 4; t++) {
    int j = tid + t * 256;
    float e = __expf(loc[t] - m);
    z += e;
    const float* wr = wsim + j * 8;
#pragma unroll
    for (int d = 0; d < 8; d++) pm[d] = fmaf(e, wr[d], pm[d]);
  }
#pragma unroll
  for (int o = 32; o > 0; o >>= 1) {
    z += __shfl_down(z, o);
#pragma unroll
    for (int d = 0; d < 8; d++) pm[d] += __shfl_down(pm[d], o);
  }
  __shared__ float sred[4][9];
  if (lane == 0) {
    sred[wid][0] = z;
#pragma unroll
    for (int d = 0; d < 8; d++) sred[wid][1 + d] = pm[d];
  }
  __syncthreads();
  if (tid < 8) {
    float zt = sred[0][0] + sred[1][0] + sred[2][0] + sred[3][0];
    float pt = sred[0][1 + tid] + sred[1][1 + tid] + sred[2][1 + tid] + sred[3][1 + tid];
    M[i * 8 + tid] = pt / zt;
  }
}

// ---------------- E(128x8) = emb(128x1024) @ M(1024x8) ----------------
__global__ __launch_bounds__(256) void k_E(const float* __restrict__ emb,
                                           const float* __restrict__ M,
                                           float* __restrict__ E) {
  __shared__ float Ml[1024 * 8];
  for (int t = threadIdx.x; t < 8192; t += 256) Ml[t] = M[t];
  __syncthreads();
  int gid = blockIdx.x * 256 + threadIdx.x;
  if (gid >= 1024) return;
  int r = gid >> 3, d = gid & 7;
  const float* er = emb + (size_t)r * 1024;
  float acc = 0.0f;
  for (int k = 0; k < 1024; k++) acc = fmaf(er[k], Ml[k * 8 + d], acc);
  E[gid] = acc;
}

// ---------------- s_emb = renorm(x @ E)  (20000x8) ----------------
__global__ __launch_bounds__(256) void k_semb(const float* __restrict__ x,
                                              const float* __restrict__ E,
                                              float* __restrict__ semb) {
  __shared__ float El[128 * 8];
  for (int t = threadIdx.x; t < 1024; t += 256) El[t] = E[t];
  __syncthreads();
  int row = blockIdx.x * 256 + threadIdx.x;
  if (row >= NN) return;
  const float* xr = x + (size_t)row * 128;
  float s[8] = {};
  for (int k = 0; k < 128; k++) {
    float xv = xr[k];
#pragma unroll
    for (int d = 0; d < 8; d++) s[d] = fmaf(xv, El[k * 8 + d], s[d]);
  }
  float n2 = 0.0f;
#pragma unroll
  for (int d = 0; d < 8; d++) n2 += s[d] * s[d];
  float n = sqrtf(n2);
  float sc = (n > 1.0f) ? 1.0f / (n + 1e-7f) : 1.0f;
#pragma unroll
  for (int d = 0; d < 8; d++) semb[(size_t)row * 8 + d] = s[d] * sc;
}

// ---------------- renorm rows of g (20000x32), in place ----------------
__global__ void k_renorm32(float* __restrict__ g) {
  int row = blockIdx.x * 256 + threadIdx.x;
  if (row >= NN) return;
  float* r = g + (size_t)row * 32;
  float v[32];
  float n2 = 0.0f;
#pragma unroll
  for (int k = 0; k < 32; k++) { v[k] = r[k]; n2 += v[k] * v[k]; }
  float n = sqrtf(n2);
  float sc = (n > 1.0f) ? 1.0f / (n + 1e-7f) : 1.0f;
#pragma unroll
  for (int k = 0; k < 32; k++) r[k] = v[k] * sc;
}

// ---------------- query head ----------------
__global__ __launch_bounds__(256) void k_query(const int* __restrict__ te,
                                               const float* __restrict__ g,
                                               const float* __restrict__ semb,
                                               const float* __restrict__ W1,
                                               const float* __restrict__ b1,
                                               const float* __restrict__ lw,
                                               const float* __restrict__ lb,
                                               float* __restrict__ out) {
  __shared__ float W1l[40 * 32];
  __shared__ float b1l[32], lwl[32];
  for (int t = threadIdx.x; t < 1280; t += 256) W1l[t] = W1[t];
  if (threadIdx.x < 32) { b1l[threadIdx.x] = b1[threadIdx.x]; lwl[threadIdx.x] = lw[threadIdx.x]; }
  __syncthreads();
  int q = blockIdx.x * 256 + threadIdx.x;
  if (q >= NQ) return;
  int i0 = te[2 * q], i1 = te[2 * q + 1];
  float feat[40];
  const float* g0 = g + (size_t)i0 * 32;
  const float* g1 = g + (size_t)i1 * 32;
#pragma unroll
  for (int k = 0; k < 32; k++) { float d = g0[k] - g1[k]; feat[k] = d * d; } // ALPHA=1
  const float* s0 = semb + (size_t)i0 * 8;
  const float* s1 = semb + (size_t)i1 * 8;
#pragma unroll
  for (int k = 0; k < 8; k++) { float d = s0[k] - s1[k]; feat[32 + k] = 0.1f * d * d; } // BETA=0.1
  float accv = lb[0];
#pragma unroll
  for (int c = 0; c < 32; c++) {
    float a = b1l[c];
#pragma unroll
    for (int k = 0; k < 40; k++) a = fmaf(feat[k], W1l[k * 32 + c], a);
    a = (a > 0.0f) ? a : 0.2f * a;            // leaky relu 0.2
    accv = fmaf(a, lwl[c], accv);
  }
  float sq = fminf(fabsf(accv), 40.0f);        // clip [0,40]
  out[q] = 1.0f / (1.0f + __expf(sq - 2.0f));  // sigmoid(2 - sq)
}

extern "C" void kernel_launch(void* const* d_in, const int* in_sizes, int n_in,
                              void* d_out, int out_size, void* d_ws, size_t ws_size,
                              hipStream_t stream) {
  const float* x     = (const float*)d_in[0];
  const float* L0    = (const float*)d_in[1];
  const float* L1    = (const float*)d_in[2];
  const int*   ei    = (const int*)d_in[3];
  const int*   te    = (const int*)d_in[4];
  const float* W1    = (const float*)d_in[5];
  const float* b1    = (const float*)d_in[6];
  const float* W2    = (const float*)d_in[7];
  const float* b2    = (const float*)d_in[8];
  const float* wsim  = (const float*)d_in[9];
  const float* embs  = (const float*)d_in[10];
  const float* wod   = (const float*)d_in[11];
  const float* wL0   = (const float*)d_in[12];
  const float* wL1   = (const float*)d_in[13];
  const float* lin1W = (const float*)d_in[14];
  const float* lin1b = (const float*)d_in[15];
  const float* linW  = (const float*)d_in[16];
  const float* linb  = (const float*)d_in[17];
  float* out = (float*)d_out;

  float* ws   = (float*)d_ws;
  float* deg  = ws;                 // 20000 (becomes dinv in place)
  float* h1   = deg + 20000;        // 20000*64
  float* acc1 = h1 + 1280000;       // 20000*64
  float* h2   = acc1 + 1280000;     // 20000*32
  float* acc2 = h2 + 640000;        // 20000*32
  float* L0r  = acc2 + 640000;      // 512*512
  float* L1r  = L0r + 262144;       // 512*512
  float* rel  = L1r + 262144;       // 512*512
  float* relo = rel + 262144;       // 512*512 (rel_)
  float* Ab   = relo + 262144;      // 512*32
  float* Bb   = Ab + 16384;         // 512*32
  float* Mm   = Bb + 16384;         // 1024*8
  float* Ee   = Mm + 8192;          // 128*8
  float* semb = Ee + 1024;          // 20000*8

  // acc1, h2, acc2 are contiguous -> one memset zeroes all (h2 overwritten anyway)
  hipMemsetAsync(acc1, 0, (size_t)(1280000 + 640000 + 640000) * sizeof(float), stream);

  // degrees -> dinv
  k_set1<<<(NN + 255) / 256, 256, 0, stream>>>(deg, NN);
  k_degedges<<<(NE + 255) / 256, 256, 0, stream>>>(ei, deg);
  k_dinv<<<(NN + 255) / 256, 256, 0, stream>>>(deg, NN);

  // GCN layer 1
  k_skinny<128, 64><<<NN / 4, 256, 0, stream>>>(x, W1, h1, NN);
  k_mp<64><<<NE / 4, 256, 0, stream>>>(ei, h1, deg, acc1);
  k_fin<64><<<(NN * 64) / 256, 256, 0, stream>>>(h1, acc1, deg, b1);

  // GCN layer 2
  k_skinny<64, 32><<<NN / 8, 256, 0, stream>>>(h1, W2, h2, NN);
  k_mp<32><<<NE / 8, 256, 0, stream>>>(ei, h2, deg, acc2);
  k_fin<32><<<(NN * 32) / 256, 256, 0, stream>>>(h2, acc2, deg, b2);
  k_renorm32<<<(NN + 255) / 256, 256, 0, stream>>>(h2);  // h2 := g

  // sim block path
  k_gemm512<<<64, 256, 0, stream>>>(L0, L0, L0r);
  k_gemm512<<<64, 256, 0, stream>>>(L1, L1, L1r);
  k_skinny_g<512, 32><<<512 / 8, 256, 0, stream>>>(L0r, wL0, Ab, 512);
  k_skinny_g<512, 32><<<512 / 8, 256, 0, stream>>>(L1r, wL1, Bb, 512);
  k_relnt<<<(512 * 512) / 256, 256, 0, stream>>>(Ab, Bb, rel);
  k_gemm512<<<64, 256, 0, stream>>>(wod, rel, relo);
  k_softmaxM<<<1024, 256, 0, stream>>>(L0r, L1r, relo, wsim, Mm);
  k_E<<<4, 256, 0, stream>>>(embs, Mm, Ee);
  k_semb<<<(NN + 255) / 256, 256, 0, stream>>>(x, Ee, semb);

  // query head
  k_query<<<(NQ + 255) / 256, 256, 0, stream>>>(te, h2, semb, lin1W, lin1b, linW, linb, out);
}

// Round 2
// 248.129 us; speedup vs baseline: 1.5244x; 1.5244x over previous
//
#include <hip/hip_runtime.h>
#include <math.h>

#define NE 320000
#define NN 20000
#define NQ 200000

// ---------------- CSR build ----------------
__global__ void k_hist(const int* __restrict__ ei, int* __restrict__ ideg) {
  int e = blockIdx.x * 256 + threadIdx.x;
  if (e < NE) atomicAdd(&ideg[ei[NE + e]], 1);
}

// single block, 1024 threads, 20 elems/thread: exclusive scan + cursor copy + dinv
__global__ __launch_bounds__(1024) void k_scan(const int* __restrict__ ideg,
                                               int* __restrict__ start,
                                               int* __restrict__ cursor,
                                               float* __restrict__ dinv) {
  int t = threadIdx.x;
  int base = t * 20;
  int cnt[20];
  int s = 0;
#pragma unroll
  for (int i = 0; i < 20; i++) {
    int idx = base + i;
    int v = (idx < NN) ? ideg[idx] : 0;
    cnt[i] = v; s += v;
  }
  int lane = t & 63, wid = t >> 6;
  int v = s;
#pragma unroll
  for (int o = 1; o < 64; o <<= 1) { int u = __shfl_up(v, o); if (lane >= o) v += u; }
  __shared__ int wsum[16];
  if (lane == 63) wsum[wid] = v;
  __syncthreads();
  if (t == 0) { int a = 0; for (int w = 0; w < 16; w++) { int tmp = wsum[w]; wsum[w] = a; a += tmp; } }
  __syncthreads();
  int off = wsum[wid] + (v - s);
#pragma unroll
  for (int i = 0; i < 20; i++) {
    int idx = base + i;
    if (idx < NN) {
      start[idx] = off; cursor[idx] = off;
      dinv[idx] = rsqrtf((float)(cnt[i] + 1));
      off += cnt[i];
    }
  }
}

__global__ void k_scatter(const int* __restrict__ ei, int* __restrict__ cursor,
                          int* __restrict__ csr) {
  int e = blockIdx.x * 256 + threadIdx.x;
  if (e >= NE) return;
  int d = ei[NE + e];
  int pos = atomicAdd(&cursor[d], 1);
  csr[pos] = ei[e];
}

// ---------------- skinny GEMM: Y(MxN)=X(MxK)@W(KxN), W in LDS, 4-col microtile ----------------
template<int K, int N>
__global__ __launch_bounds__(256) void k_xw(const float* __restrict__ X,
                                            const float* __restrict__ W,
                                            float* __restrict__ Y, int M) {
  constexpr int TPR = N / 4;
  constexpr int ROWS = 256 / TPR;
  __shared__ float Wl[K * N];
  for (int t = threadIdx.x; t < K * N / 4; t += 256)
    ((float4*)Wl)[t] = ((const float4*)W)[t];
  __syncthreads();
  int r = blockIdx.x * ROWS + threadIdx.x / TPR;
  int c4 = (threadIdx.x % TPR) * 4;
  if (r >= M) return;
  const float4* xr4 = (const float4*)(X + (size_t)r * K);
  float a0 = 0, a1 = 0, a2 = 0, a3 = 0;
#pragma unroll 4
  for (int k4 = 0; k4 < K / 4; k4++) {
    float4 xv = xr4[k4];
    int kb = k4 * 4;
    { const float4 w = *(const float4*)&Wl[(kb + 0) * N + c4];
      a0 = fmaf(xv.x, w.x, a0); a1 = fmaf(xv.x, w.y, a1); a2 = fmaf(xv.x, w.z, a2); a3 = fmaf(xv.x, w.w, a3); }
    { const float4 w = *(const float4*)&Wl[(kb + 1) * N + c4];
      a0 = fmaf(xv.y, w.x, a0); a1 = fmaf(xv.y, w.y, a1); a2 = fmaf(xv.y, w.z, a2); a3 = fmaf(xv.y, w.w, a3); }
    { const float4 w = *(const float4*)&Wl[(kb + 2) * N + c4];
      a0 = fmaf(xv.z, w.x, a0); a1 = fmaf(xv.z, w.y, a1); a2 = fmaf(xv.z, w.z, a2); a3 = fmaf(xv.z, w.w, a3); }
    { const float4 w = *(const float4*)&Wl[(kb + 3) * N + c4];
      a0 = fmaf(xv.w, w.x, a0); a1 = fmaf(xv.w, w.y, a1); a2 = fmaf(xv.w, w.z, a2); a3 = fmaf(xv.w, w.w, a3); }
  }
  float4 o; o.x = a0; o.y = a1; o.z = a2; o.w = a3;
  *(float4*)&Y[(size_t)r * N + c4] = o;
}

// ---------------- gather aggregation (fused finalize), C=64: wave per node ----------------
__global__ __launch_bounds__(256) void k_gather64(const int* __restrict__ start,
                                                  const int* __restrict__ ideg,
                                                  const int* __restrict__ csr,
                                                  const float* __restrict__ hraw,
                                                  const float* __restrict__ dinv,
                                                  const float* __restrict__ b,
                                                  float* __restrict__ hout) {
  int lane = threadIdx.x & 63;
  int n = blockIdx.x * 4 + (threadIdx.x >> 6);
  int s0 = start[n], cnt = ideg[n];
  float acc = 0.0f;
  int k = 0;
  for (; k + 1 < cnt; k += 2) {
    int sA = csr[s0 + k], sB = csr[s0 + k + 1];
    float dA = dinv[sA], dB = dinv[sB];
    float vA = hraw[(size_t)sA * 64 + lane];
    float vB = hraw[(size_t)sB * 64 + lane];
    acc = fmaf(vA, dA, acc);
    acc = fmaf(vB, dB, acc);
  }
  if (k < cnt) {
    int sA = csr[s0 + k];
    acc = fmaf(hraw[(size_t)sA * 64 + lane], dinv[sA], acc);
  }
  float dn = dinv[n];
  float v = fmaf(acc, dn, hraw[(size_t)n * 64 + lane] * dn * dn) + b[lane];
  hout[(size_t)n * 64 + lane] = fmaxf(v, 0.0f);
}

// C=32: half-wave per node, fused renorm
__global__ __launch_bounds__(256) void k_gather32ren(const int* __restrict__ start,
                                                     const int* __restrict__ ideg,
                                                     const int* __restrict__ csr,
                                                     const float* __restrict__ hraw,
                                                     const float* __restrict__ dinv,
                                                     const float* __restrict__ b,
                                                     float* __restrict__ g) {
  int lane = threadIdx.x & 31;
  int n = blockIdx.x * 8 + (threadIdx.x >> 5);
  int s0 = start[n], cnt = ideg[n];
  float acc = 0.0f;
  int k = 0;
  for (; k + 1 < cnt; k += 2) {
    int sA = csr[s0 + k], sB = csr[s0 + k + 1];
    float dA = dinv[sA], dB = dinv[sB];
    float vA = hraw[(size_t)sA * 32 + lane];
    float vB = hraw[(size_t)sB * 32 + lane];
    acc = fmaf(vA, dA, acc);
    acc = fmaf(vB, dB, acc);
  }
  if (k < cnt) {
    int sA = csr[s0 + k];
    acc = fmaf(hraw[(size_t)sA * 32 + lane], dinv[sA], acc);
  }
  float dn = dinv[n];
  float v = fmaf(acc, dn, hraw[(size_t)n * 32 + lane] * dn * dn) + b[lane];
  v = fmaxf(v, 0.0f);
  // renorm across the 32 lanes of this half-wave
  float n2 = v * v;
#pragma unroll
  for (int o = 16; o > 0; o >>= 1) n2 += __shfl_xor(n2, o);
  float nrm = sqrtf(n2);
  float sc = (nrm > 1.0f) ? 1.0f / (nrm + 1e-7f) : 1.0f;
  g[(size_t)n * 32 + lane] = v * sc;
}

// ---------------- 512x512x512 f32 GEMM x2 (L0r=L0@L0, L1r=L1@L1) ----------------
__global__ __launch_bounds__(256) void k_gemm512x2(const float* __restrict__ L0,
                                                   const float* __restrict__ L1,
                                                   float* __restrict__ L0r,
                                                   float* __restrict__ L1r) {
  const float* A = (blockIdx.x < 64) ? L0 : L1;
  float* C = (blockIdx.x < 64) ? L0r : L1r;
  int bb = blockIdx.x & 63;
  __shared__ float As[16][68];
  __shared__ float Bs[16][68];
  int tid = threadIdx.x;
  int tx = tid & 15, ty = tid >> 4;
  int brow = (bb >> 3) * 64;
  int bcol = (bb & 7) * 64;
  float c[4][4] = {};
  for (int k0 = 0; k0 < 512; k0 += 16) {
#pragma unroll
    for (int t = 0; t < 4; t++) {
      int idx = tid * 4 + t;
      int r = idx >> 4, cc = idx & 15;
      As[cc][r] = A[(size_t)(brow + r) * 512 + k0 + cc];
      int r2 = idx >> 6, c2 = idx & 63;
      Bs[r2][c2] = A[(size_t)(k0 + r2) * 512 + bcol + c2];
    }
    __syncthreads();
#pragma unroll
    for (int k = 0; k < 16; k++) {
      float a0 = As[k][ty * 4 + 0], a1 = As[k][ty * 4 + 1];
      float a2 = As[k][ty * 4 + 2], a3 = As[k][ty * 4 + 3];
      float b0 = Bs[k][tx * 4 + 0], b1 = Bs[k][tx * 4 + 1];
      float b2 = Bs[k][tx * 4 + 2], b3 = Bs[k][tx * 4 + 3];
      c[0][0] = fmaf(a0, b0, c[0][0]); c[0][1] = fmaf(a0, b1, c[0][1]);
      c[0][2] = fmaf(a0, b2, c[0][2]); c[0][3] = fmaf(a0, b3, c[0][3]);
      c[1][0] = fmaf(a1, b0, c[1][0]); c[1][1] = fmaf(a1, b1, c[1][1]);
      c[1][2] = fmaf(a1, b2, c[1][2]); c[1][3] = fmaf(a1, b3, c[1][3]);
      c[2][0] = fmaf(a2, b0, c[2][0]); c[2][1] = fmaf(a2, b1, c[2][1]);
      c[2][2] = fmaf(a2, b2, c[2][2]); c[2][3] = fmaf(a2, b3, c[2][3]);
      c[3][0] = fmaf(a3, b0, c[3][0]); c[3][1] = fmaf(a3, b1, c[3][1]);
      c[3][2] = fmaf(a3, b2, c[3][2]); c[3][3] = fmaf(a3, b3, c[3][3]);
    }
    __syncthreads();
  }
#pragma unroll
  for (int i = 0; i < 4; i++)
#pragma unroll
    for (int j = 0; j < 4; j++)
      C[(size_t)(brow + ty * 4 + i) * 512 + bcol + tx * 4 + j] = c[i][j];
}

// ---------------- Ab = L0r@wL0, Bb = L1r@wL1 (K=512,N=32, W streamed) ----------------
__device__ __forceinline__ void sk512_body(const float* X, const float* W, float* Y, int b) {
  int r = b * 32 + threadIdx.x / 8;
  int c4 = (threadIdx.x % 8) * 4;
  const float4* xr4 = (const float4*)(X + (size_t)r * 512);
  float a0 = 0, a1 = 0, a2 = 0, a3 = 0;
#pragma unroll 2
  for (int k4 = 0; k4 < 128; k4++) {
    float4 xv = xr4[k4];
    int kb = k4 * 4;
    { const float4 w = *(const float4*)&W[(kb + 0) * 32 + c4];
      a0 = fmaf(xv.x, w.x, a0); a1 = fmaf(xv.x, w.y, a1); a2 = fmaf(xv.x, w.z, a2); a3 = fmaf(xv.x, w.w, a3); }
    { const float4 w = *(const float4*)&W[(kb + 1) * 32 + c4];
      a0 = fmaf(xv.y, w.x, a0); a1 = fmaf(xv.y, w.y, a1); a2 = fmaf(xv.y, w.z, a2); a3 = fmaf(xv.y, w.w, a3); }
    { const float4 w = *(const float4*)&W[(kb + 2) * 32 + c4];
      a0 = fmaf(xv.z, w.x, a0); a1 = fmaf(xv.z, w.y, a1); a2 = fmaf(xv.z, w.z, a2); a3 = fmaf(xv.z, w.w, a3); }
    { const float4 w = *(const float4*)&W[(kb + 3) * 32 + c4];
      a0 = fmaf(xv.w, w.x, a0); a1 = fmaf(xv.w, w.y, a1); a2 = fmaf(xv.w, w.z, a2); a3 = fmaf(xv.w, w.w, a3); }
  }
  float4 o; o.x = a0; o.y = a1; o.z = a2; o.w = a3;
  *(float4*)&Y[(size_t)r * 32 + c4] = o;
}

__global__ __launch_bounds__(256) void k_ab(const float* __restrict__ L0r,
                                            const float* __restrict__ L1r,
                                            const float* __restrict__ wL0,
                                            const float* __restrict__ wL1,
                                            float* __restrict__ Ab,
                                            float* __restrict__ Bb) {
  int bb = blockIdx.x;
  if (bb < 16) sk512_body(L0r, wL0, Ab, bb);
  else         sk512_body(L1r, wL1, Bb, bb - 16);
}

__global__ __launch_bounds__(256) void k_ab2(const float* __restrict__ wod,
                                             const float* __restrict__ Ab,
                                             float* __restrict__ Ab2) {
  sk512_body(wod, Ab, Ab2, blockIdx.x);
}

// ---------------- rel_ = Ab2(512x32) @ Bb(512x32)^T ----------------
__global__ void k_relnt(const float* __restrict__ A, const float* __restrict__ B,
                        float* __restrict__ C) {
  int gid = blockIdx.x * 256 + threadIdx.x;
  int i = gid >> 9, j = gid & 511;
  const float4* ar = (const float4*)(A + i * 32);
  const float4* br = (const float4*)(B + j * 32);
  float acc = 0.0f;
#pragma unroll
  for (int t = 0; t < 8; t++) {
    float4 a = ar[t], b = br[t];
    acc = fmaf(a.x, b.x, acc); acc = fmaf(a.y, b.y, acc);
    acc = fmaf(a.z, b.z, acc); acc = fmaf(a.w, b.w, acc);
  }
  C[gid] = acc;
}

// ---------------- fused row-softmax(relu(S)) @ weights_sim -> M (1024x8) ----------------
__global__ __launch_bounds__(256) void k_softmaxM(const float* __restrict__ L0r,
                                                  const float* __restrict__ L1r,
                                                  const float* __restrict__ rel_,
                                                  const float* __restrict__ wsim,
                                                  float* __restrict__ M) {
  int i = blockIdx.x;
  int tid = threadIdx.x;
  float loc[4];
  float mymax = 0.0f;
#pragma unroll
  for (int t = 0; t < 4; t++) {
    int j = tid + t * 256;
    float v;
    if (i < 512) v = (j < 512) ? L0r[i * 512 + j] : rel_[i * 512 + (j - 512)];
    else {
      int r = i - 512;
      v = (j < 512) ? rel_[j * 512 + r] : L1r[r * 512 + (j - 512)];
    }
    v = fmaxf(v, 0.0f);
    loc[t] = v;
    mymax = fmaxf(mymax, v);
  }
#pragma unroll
  for (int o = 32; o > 0; o >>= 1) mymax = fmaxf(mymax, __shfl_down(mymax, o));
  __shared__ float smax[4];
  int wid = tid >> 6, lane = tid & 63;
  if (lane == 0) smax[wid] = mymax;
  __syncthreads();
  float m = fmaxf(fmaxf(smax[0], smax[1]), fmaxf(smax[2], smax[3]));

  float z = 0.0f, pm[8] = {};
#pragma unroll
  for (int t = 0; t < 4; t++) {
    int j = tid + t * 256;
    float e = __expf(loc[t] - m);
    z += e;
    const float* wr = wsim + j * 8;
#pragma unroll
    for (int d = 0; d < 8; d++) pm[d] = fmaf(e, wr[d], pm[d]);
  }
#pragma unroll
  for (int o = 32; o > 0; o >>= 1) {
    z += __shfl_down(z, o);
#pragma unroll
    for (int d = 0; d < 8; d++) pm[d] += __shfl_down(pm[d], o);
  }
  __shared__ float sred[4][9];
  if (lane == 0) {
    sred[wid][0] = z;
#pragma unroll
    for (int d = 0; d < 8; d++) sred[wid][1 + d] = pm[d];
  }
  __syncthreads();
  if (tid < 8) {
    float zt = sred[0][0] + sred[1][0] + sred[2][0] + sred[3][0];
    float pt = sred[0][1 + tid] + sred[1][1 + tid] + sred[2][1 + tid] + sred[3][1 + tid];
    M[i * 8 + tid] = pt / zt;
  }
}

// ---------------- E(128x8) = emb(128x1024) @ M(1024x8): 32 blocks, shfl reduce ----------------
__global__ __launch_bounds__(256) void k_E(const float* __restrict__ emb,
                                           const float* __restrict__ M,
                                           float* __restrict__ E) {
  __shared__ float Ml[8192];
  for (int t = threadIdx.x; t < 2048; t += 256)
    ((float4*)Ml)[t] = ((const float4*)M)[t];
  __syncthreads();
  int lane = threadIdx.x & 63;
  int r = blockIdx.x * 4 + (threadIdx.x >> 6);
  const float* er = emb + (size_t)r * 1024;
  float acc[8] = {};
  for (int it = 0; it < 16; it++) {
    int k = lane + it * 64;
    float e = er[k];
    const float4* mp = (const float4*)&Ml[k * 8];
    float4 m0 = mp[0], m1 = mp[1];
    acc[0] = fmaf(e, m0.x, acc[0]); acc[1] = fmaf(e, m0.y, acc[1]);
    acc[2] = fmaf(e, m0.z, acc[2]); acc[3] = fmaf(e, m0.w, acc[3]);
    acc[4] = fmaf(e, m1.x, acc[4]); acc[5] = fmaf(e, m1.y, acc[5]);
    acc[6] = fmaf(e, m1.z, acc[6]); acc[7] = fmaf(e, m1.w, acc[7]);
  }
#pragma unroll
  for (int o = 32; o > 0; o >>= 1)
#pragma unroll
    for (int d = 0; d < 8; d++) acc[d] += __shfl_down(acc[d], o);
  if (lane == 0)
#pragma unroll
    for (int d = 0; d < 8; d++) E[r * 8 + d] = acc[d];
}

// ---------------- s_emb = renorm(x @ E)  (20000x8) ----------------
__global__ __launch_bounds__(256) void k_semb(const float* __restrict__ x,
                                              const float* __restrict__ E,
                                              float* __restrict__ semb) {
  __shared__ float El[1024];
  for (int t = threadIdx.x; t < 256; t += 256)
    ((float4*)El)[t] = ((const float4*)E)[t];
  __syncthreads();
  int row = blockIdx.x * 256 + threadIdx.x;
  if (row >= NN) return;
  const float4* xr4 = (const float4*)(x + (size_t)row * 128);
  float s[8] = {};
#pragma unroll 4
  for (int k4 = 0; k4 < 32; k4++) {
    float4 xv = xr4[k4];
    int kb = k4 * 4;
#pragma unroll
    for (int u = 0; u < 4; u++) {
      float xk = (u == 0) ? xv.x : (u == 1) ? xv.y : (u == 2) ? xv.z : xv.w;
      const float4* ep = (const float4*)&El[(kb + u) * 8];
      float4 e0 = ep[0], e1 = ep[1];
      s[0] = fmaf(xk, e0.x, s[0]); s[1] = fmaf(xk, e0.y, s[1]);
      s[2] = fmaf(xk, e0.z, s[2]); s[3] = fmaf(xk, e0.w, s[3]);
      s[4] = fmaf(xk, e1.x, s[4]); s[5] = fmaf(xk, e1.y, s[5]);
      s[6] = fmaf(xk, e1.z, s[6]); s[7] = fmaf(xk, e1.w, s[7]);
    }
  }
  float n2 = 0.0f;
#pragma unroll
  for (int d = 0; d < 8; d++) n2 += s[d] * s[d];
  float n = sqrtf(n2);
  float sc = (n > 1.0f) ? 1.0f / (n + 1e-7f) : 1.0f;
#pragma unroll
  for (int d = 0; d < 8; d++) semb[(size_t)row * 8 + d] = s[d] * sc;
}

// ---------------- query head: W1/b1/lw via uniform scalar loads ----------------
__global__ __launch_bounds__(256) void k_query(const int* __restrict__ te,
                                               const float* __restrict__ g,
                                               const float* __restrict__ semb,
                                               const float* __restrict__ W1,
                                               const float* __restrict__ b1,
                                               const float* __restrict__ lw,
                                               const float* __restrict__ lb,
                                               float* __restrict__ out) {
  int q = blockIdx.x * 256 + threadIdx.x;
  if (q >= NQ) return;
  const int2 p = ((const int2*)te)[q];
  int i0 = p.x, i1 = p.y;
  float feat[40];
  const float4* g0 = (const float4*)(g + (size_t)i0 * 32);
  const float4* g1 = (const float4*)(g + (size_t)i1 * 32);
#pragma unroll
  for (int t = 0; t < 8; t++) {
    float4 a = g0[t], b = g1[t];
    float d0 = a.x - b.x, d1 = a.y - b.y, d2 = a.z - b.z, d3 = a.w - b.w;
    feat[t * 4 + 0] = d0 * d0; feat[t * 4 + 1] = d1 * d1;
    feat[t * 4 + 2] = d2 * d2; feat[t * 4 + 3] = d3 * d3;
  }
  const float4* s0 = (const float4*)(semb + (size_t)i0 * 8);
  const float4* s1 = (const float4*)(semb + (size_t)i1 * 8);
#pragma unroll
  for (int t = 0; t < 2; t++) {
    float4 a = s0[t], b = s1[t];
    float d0 = a.x - b.x, d1 = a.y - b.y, d2 = a.z - b.z, d3 = a.w - b.w;
    feat[32 + t * 4 + 0] = 0.1f * d0 * d0; feat[32 + t * 4 + 1] = 0.1f * d1 * d1;
    feat[32 + t * 4 + 2] = 0.1f * d2 * d2; feat[32 + t * 4 + 3] = 0.1f * d3 * d3;
  }
  float acc[32];
#pragma unroll
  for (int c = 0; c < 32; c++) acc[c] = b1[c];        // uniform -> s_load
#pragma unroll
  for (int k = 0; k < 40; k++) {
    float f = feat[k];
#pragma unroll
    for (int c = 0; c < 32; c++) acc[c] = fmaf(f, W1[k * 32 + c], acc[c]); // uniform -> s_load
  }
  float accv = lb[0];
#pragma unroll
  for (int c = 0; c < 32; c++) {
    float a = acc[c];
    a = (a > 0.0f) ? a : 0.2f * a;
    accv = fmaf(a, lw[c], accv);
  }
  float sq = fminf(fabsf(accv), 40.0f);
  out[q] = 1.0f / (1.0f + __expf(sq - 2.0f));
}

extern "C" void kernel_launch(void* const* d_in, const int* in_sizes, int n_in,
                              void* d_out, int out_size, void* d_ws, size_t ws_size,
                              hipStream_t stream) {
  const float* x     = (const float*)d_in[0];
  const float* L0    = (const float*)d_in[1];
  const float* L1    = (const float*)d_in[2];
  const int*   ei    = (const int*)d_in[3];
  const int*   te    = (const int*)d_in[4];
  const float* W1    = (const float*)d_in[5];
  const float* b1    = (const float*)d_in[6];
  const float* W2    = (const float*)d_in[7];
  const float* b2    = (const float*)d_in[8];
  const float* wsim  = (const float*)d_in[9];
  const float* embs  = (const float*)d_in[10];
  const float* wod   = (const float*)d_in[11];
  const float* wL0   = (const float*)d_in[12];
  const float* wL1   = (const float*)d_in[13];
  const float* lin1W = (const float*)d_in[14];
  const float* lin1b = (const float*)d_in[15];
  const float* linW  = (const float*)d_in[16];
  const float* linb  = (const float*)d_in[17];
  float* out = (float*)d_out;

  int*   ideg   = (int*)d_ws;             // 20000
  int*   start  = ideg + 20000;           // 20000
  int*   cursor = start + 20000;          // 20000
  int*   csr    = cursor + 20000;         // 320000
  float* dinv   = (float*)(csr + 320000); // 20000
  float* h1raw  = dinv + 20000;           // 1,280,000
  float* h1     = h1raw + 1280000;        // 1,280,000
  float* h2raw  = h1raw;                  // alias: h1raw dead after gather64
  float* g      = h1 + 1280000;           // 640,000
  float* L0r    = g + 640000;             // 262,144
  float* L1r    = L0r + 262144;           // 262,144
  float* relo   = L1r + 262144;           // 262,144
  float* Ab     = relo + 262144;          // 16,384
  float* Bb     = Ab + 16384;             // 16,384
  float* Ab2    = Bb + 16384;             // 16,384
  float* Mm     = Ab2 + 16384;            // 8,192
  float* Ee     = Mm + 8192;              // 1,024
  float* semb   = Ee + 1024;              // 160,000

  // CSR build
  hipMemsetAsync(ideg, 0, 20000 * sizeof(int), stream);
  k_hist<<<1250, 256, 0, stream>>>(ei, ideg);
  k_scan<<<1, 1024, 0, stream>>>(ideg, start, cursor, dinv);
  k_scatter<<<1250, 256, 0, stream>>>(ei, cursor, csr);

  // sim-block chain
  k_gemm512x2<<<128, 256, 0, stream>>>(L0, L1, L0r, L1r);
  k_ab<<<32, 256, 0, stream>>>(L0r, L1r, wL0, wL1, Ab, Bb);
  k_ab2<<<16, 256, 0, stream>>>(wod, Ab, Ab2);
  k_relnt<<<1024, 256, 0, stream>>>(Ab2, Bb, relo);
  k_softmaxM<<<1024, 256, 0, stream>>>(L0r, L1r, relo, wsim, Mm);
  k_E<<<32, 256, 0, stream>>>(embs, Mm, Ee);
  k_semb<<<79, 256, 0, stream>>>(x, Ee, semb);

  // GCN
  k_xw<128, 64><<<1250, 256, 0, stream>>>(x, W1, h1raw, NN);
  k_gather64<<<5000, 256, 0, stream>>>(start, ideg, csr, h1raw, dinv, b1, h1);
  k_xw<64, 32><<<625, 256, 0, stream>>>(h1, W2, h2raw, NN);
  k_gather32ren<<<2500, 256, 0, stream>>>(start, ideg, csr, h2raw, dinv, b2, g);

  // query head
  k_query<<<782, 256, 0, stream>>>(te, g, semb, lin1W, lin1b, linW, linb, out);
}

// Round 3
// 227.320 us; speedup vs baseline: 1.6639x; 1.0915x over previous
//
#include <hip/hip_runtime.h>
#include <math.h>

#define NE 320000
#define NN 20000
#define NQ 200000

// ================= bodies =================

// ---- 512x512x512 f32 GEMM (C = A@A), 64x64 tile, 4x4 microtile ----
__device__ __forceinline__ void gemm512_body(char* smem, const float* __restrict__ A,
                                             float* __restrict__ C, int bb) {
  float (*As)[68] = (float(*)[68])smem;                 // 16 x 68
  float (*Bs)[68] = (float(*)[68])(smem + 16 * 68 * 4); // 16 x 68
  int tid = threadIdx.x;
  int tx = tid & 15, ty = tid >> 4;
  int brow = (bb >> 3) * 64;
  int bcol = (bb & 7) * 64;
  float c[4][4] = {};
  for (int k0 = 0; k0 < 512; k0 += 16) {
#pragma unroll
    for (int t = 0; t < 4; t++) {
      int idx = tid * 4 + t;
      int r = idx >> 4, cc = idx & 15;
      As[cc][r] = A[(size_t)(brow + r) * 512 + k0 + cc];
      int r2 = idx >> 6, c2 = idx & 63;
      Bs[r2][c2] = A[(size_t)(k0 + r2) * 512 + bcol + c2];
    }
    __syncthreads();
#pragma unroll
    for (int k = 0; k < 16; k++) {
      float a0 = As[k][ty * 4 + 0], a1 = As[k][ty * 4 + 1];
      float a2 = As[k][ty * 4 + 2], a3 = As[k][ty * 4 + 3];
      float b0 = Bs[k][tx * 4 + 0], b1 = Bs[k][tx * 4 + 1];
      float b2 = Bs[k][tx * 4 + 2], b3 = Bs[k][tx * 4 + 3];
      c[0][0] = fmaf(a0, b0, c[0][0]); c[0][1] = fmaf(a0, b1, c[0][1]);
      c[0][2] = fmaf(a0, b2, c[0][2]); c[0][3] = fmaf(a0, b3, c[0][3]);
      c[1][0] = fmaf(a1, b0, c[1][0]); c[1][1] = fmaf(a1, b1, c[1][1]);
      c[1][2] = fmaf(a1, b2, c[1][2]); c[1][3] = fmaf(a1, b3, c[1][3]);
      c[2][0] = fmaf(a2, b0, c[2][0]); c[2][1] = fmaf(a2, b1, c[2][1]);
      c[2][2] = fmaf(a2, b2, c[2][2]); c[2][3] = fmaf(a2, b3, c[2][3]);
      c[3][0] = fmaf(a3, b0, c[3][0]); c[3][1] = fmaf(a3, b1, c[3][1]);
      c[3][2] = fmaf(a3, b2, c[3][2]); c[3][3] = fmaf(a3, b3, c[3][3]);
    }
    __syncthreads();
  }
#pragma unroll
  for (int i = 0; i < 4; i++)
#pragma unroll
    for (int j = 0; j < 4; j++)
      C[(size_t)(brow + ty * 4 + i) * 512 + bcol + tx * 4 + j] = c[i][j];
}

// ---- skinny GEMM body: Y(MxN)=X(MxK)@W(KxN), W staged in LDS ----
template<int K, int N>
__device__ __forceinline__ void xw_body(char* smem, const float* __restrict__ X,
                                        const float* __restrict__ W,
                                        float* __restrict__ Y, int bb) {
  constexpr int TPR = N / 4;
  constexpr int ROWS = 256 / TPR;
  float* Wl = (float*)smem;
  for (int t = threadIdx.x; t < K * N / 4; t += 256)
    ((float4*)Wl)[t] = ((const float4*)W)[t];
  __syncthreads();
  int r = bb * ROWS + threadIdx.x / TPR;
  int c4 = (threadIdx.x % TPR) * 4;
  if (r >= NN) return;
  const float4* xr4 = (const float4*)(X + (size_t)r * K);
  float a0 = 0, a1 = 0, a2 = 0, a3 = 0;
#pragma unroll 4
  for (int k4 = 0; k4 < K / 4; k4++) {
    float4 xv = xr4[k4];
    int kb = k4 * 4;
    { const float4 w = *(const float4*)&Wl[(kb + 0) * N + c4];
      a0 = fmaf(xv.x, w.x, a0); a1 = fmaf(xv.x, w.y, a1); a2 = fmaf(xv.x, w.z, a2); a3 = fmaf(xv.x, w.w, a3); }
    { const float4 w = *(const float4*)&Wl[(kb + 1) * N + c4];
      a0 = fmaf(xv.y, w.x, a0); a1 = fmaf(xv.y, w.y, a1); a2 = fmaf(xv.y, w.z, a2); a3 = fmaf(xv.y, w.w, a3); }
    { const float4 w = *(const float4*)&Wl[(kb + 2) * N + c4];
      a0 = fmaf(xv.z, w.x, a0); a1 = fmaf(xv.z, w.y, a1); a2 = fmaf(xv.z, w.z, a2); a3 = fmaf(xv.z, w.w, a3); }
    { const float4 w = *(const float4*)&Wl[(kb + 3) * N + c4];
      a0 = fmaf(xv.w, w.x, a0); a1 = fmaf(xv.w, w.y, a1); a2 = fmaf(xv.w, w.z, a2); a3 = fmaf(xv.w, w.w, a3); }
  }
  float4 o; o.x = a0; o.y = a1; o.z = a2; o.w = a3;
  *(float4*)&Y[(size_t)r * N + c4] = o;
}

// ---- Ab-style body: Y(512x32) = X(512x512)@W(512x32), W streamed ----
__device__ __forceinline__ void sk512_body(const float* X, const float* W, float* Y, int b) {
  int r = b * 32 + threadIdx.x / 8;
  int c4 = (threadIdx.x % 8) * 4;
  const float4* xr4 = (const float4*)(X + (size_t)r * 512);
  float a0 = 0, a1 = 0, a2 = 0, a3 = 0;
#pragma unroll 2
  for (int k4 = 0; k4 < 128; k4++) {
    float4 xv = xr4[k4];
    int kb = k4 * 4;
    { const float4 w = *(const float4*)&W[(kb + 0) * 32 + c4];
      a0 = fmaf(xv.x, w.x, a0); a1 = fmaf(xv.x, w.y, a1); a2 = fmaf(xv.x, w.z, a2); a3 = fmaf(xv.x, w.w, a3); }
    { const float4 w = *(const float4*)&W[(kb + 1) * 32 + c4];
      a0 = fmaf(xv.y, w.x, a0); a1 = fmaf(xv.y, w.y, a1); a2 = fmaf(xv.y, w.z, a2); a3 = fmaf(xv.y, w.w, a3); }
    { const float4 w = *(const float4*)&W[(kb + 2) * 32 + c4];
      a0 = fmaf(xv.z, w.x, a0); a1 = fmaf(xv.z, w.y, a1); a2 = fmaf(xv.z, w.z, a2); a3 = fmaf(xv.z, w.w, a3); }
    { const float4 w = *(const float4*)&W[(kb + 3) * 32 + c4];
      a0 = fmaf(xv.w, w.x, a0); a1 = fmaf(xv.w, w.y, a1); a2 = fmaf(xv.w, w.z, a2); a3 = fmaf(xv.w, w.w, a3); }
  }
  float4 o; o.x = a0; o.y = a1; o.z = a2; o.w = a3;
  *(float4*)&Y[(size_t)r * 32 + c4] = o;
}

// ================= MEGA kernels =================

// L1: gemm512 x2 (blocks 0..127) | xw1 (128..1377) | zero ideg (1378..1456)
__global__ __launch_bounds__(256) void mega1(const float* __restrict__ L0,
                                             const float* __restrict__ L1,
                                             float* __restrict__ L0r,
                                             float* __restrict__ L1r,
                                             const float* __restrict__ x,
                                             const float* __restrict__ W1,
                                             float* __restrict__ h1raw,
                                             int* __restrict__ ideg) {
  __shared__ __align__(16) char smem[32768];
  int b = blockIdx.x;
  if (b < 128) {
    const float* A = (b < 64) ? L0 : L1;
    float* C = (b < 64) ? L0r : L1r;
    gemm512_body(smem, A, C, b & 63);
  } else if (b < 1378) {
    xw_body<128, 64>(smem, x, W1, h1raw, b - 128);
  } else {
    int i = (b - 1378) * 256 + threadIdx.x;
    if (i < NN) ideg[i] = 0;
  }
}

// L2: ab (blocks 0..31) | hist (32..1281)
__global__ __launch_bounds__(256) void mega2(const float* __restrict__ L0r,
                                             const float* __restrict__ L1r,
                                             const float* __restrict__ wL0,
                                             const float* __restrict__ wL1,
                                             float* __restrict__ Ab,
                                             float* __restrict__ Bb,
                                             const int* __restrict__ ei,
                                             int* __restrict__ ideg) {
  int b = blockIdx.x;
  if (b < 16) sk512_body(L0r, wL0, Ab, b);
  else if (b < 32) sk512_body(L1r, wL1, Bb, b - 16);
  else {
    int e = (b - 32) * 256 + threadIdx.x;
    if (e < NE) atomicAdd(&ideg[ei[NE + e]], 1);
  }
}

// L3: ab2 (blocks 0..15) | scan (block 16)
__global__ __launch_bounds__(256) void mega3(const float* __restrict__ wod,
                                             const float* __restrict__ Ab,
                                             float* __restrict__ Ab2,
                                             const int* __restrict__ ideg,
                                             int* __restrict__ start,
                                             int* __restrict__ cursor,
                                             float* __restrict__ dinv) {
  int b = blockIdx.x;
  if (b < 16) { sk512_body(wod, Ab, Ab2, b); return; }
  // ---- exclusive scan over 20000 degrees, 256 threads x 79 elems ----
  __shared__ int wsum[4];
  int t = threadIdx.x;
  int s = 0;
#pragma unroll 1
  for (int i = 0; i < 79; i++) {
    int idx = t * 79 + i;
    if (idx < NN) s += ideg[idx];
  }
  int lane = t & 63, wid = t >> 6;
  int v = s;
#pragma unroll
  for (int o = 1; o < 64; o <<= 1) { int u = __shfl_up(v, o); if (lane >= o) v += u; }
  if (lane == 63) wsum[wid] = v;
  __syncthreads();
  int wbase = 0;
  for (int w = 0; w < wid; w++) wbase += wsum[w];
  int off = wbase + v - s;  // exclusive prefix for this thread's range
#pragma unroll 1
  for (int i = 0; i < 79; i++) {
    int idx = t * 79 + i;
    if (idx < NN) {
      int c = ideg[idx];
      start[idx] = off; cursor[idx] = off;
      dinv[idx] = rsqrtf((float)(c + 1));
      off += c;
    }
  }
}

// L4: softmaxM with fused rel_ (blocks 0..1023) | scatter (1024..2273)
__global__ __launch_bounds__(256) void mega4(const float* __restrict__ L0r,
                                             const float* __restrict__ L1r,
                                             const float* __restrict__ Ab2,
                                             const float* __restrict__ Bb,
                                             const float* __restrict__ wsim,
                                             float* __restrict__ M,
                                             const int* __restrict__ ei,
                                             int* __restrict__ cursor,
                                             int* __restrict__ csr) {
  int b = blockIdx.x;
  if (b >= 1024) {
    int e = (b - 1024) * 256 + threadIdx.x;
    if (e < NE) {
      int d = ei[NE + e];
      int pos = atomicAdd(&cursor[d], 1);
      csr[pos] = ei[e];
    }
    return;
  }
  int i = b;
  int tid = threadIdx.x;
  // uniform row for the fused rel_ dot: Ab2[i] (upper) or Bb[i-512] (lower)
  float urow[32];
  {
    const float4* up = (const float4*)((i < 512) ? (Ab2 + i * 32) : (Bb + (i - 512) * 32));
#pragma unroll
    for (int q = 0; q < 8; q++) {
      float4 u4 = up[q];
      urow[q * 4 + 0] = u4.x; urow[q * 4 + 1] = u4.y;
      urow[q * 4 + 2] = u4.z; urow[q * 4 + 3] = u4.w;
    }
  }
  float loc[4];
  float mymax = 0.0f;  // post-relu >= 0
#pragma unroll
  for (int t = 0; t < 4; t++) {
    int j = tid + t * 256;
    float v;
    if (i < 512) {
      if (j < 512) v = L0r[i * 512 + j];
      else {
        const float4* bj = (const float4*)(Bb + (j - 512) * 32);
        float acc = 0.0f;
#pragma unroll
        for (int q = 0; q < 8; q++) {
          float4 b4 = bj[q];
          acc = fmaf(urow[q * 4 + 0], b4.x, acc); acc = fmaf(urow[q * 4 + 1], b4.y, acc);
          acc = fmaf(urow[q * 4 + 2], b4.z, acc); acc = fmaf(urow[q * 4 + 3], b4.w, acc);
        }
        v = acc;
      }
    } else {
      int r = i - 512;
      if (j < 512) {
        const float4* aj = (const float4*)(Ab2 + j * 32);
        float acc = 0.0f;
#pragma unroll
        for (int q = 0; q < 8; q++) {
          float4 a4 = aj[q];
          acc = fmaf(urow[q * 4 + 0], a4.x, acc); acc = fmaf(urow[q * 4 + 1], a4.y, acc);
          acc = fmaf(urow[q * 4 + 2], a4.z, acc); acc = fmaf(urow[q * 4 + 3], a4.w, acc);
        }
        v = acc;
      } else v = L1r[r * 512 + (j - 512)];
    }
    v = fmaxf(v, 0.0f);
    loc[t] = v;
    mymax = fmaxf(mymax, v);
  }
#pragma unroll
  for (int o = 32; o > 0; o >>= 1) mymax = fmaxf(mymax, __shfl_down(mymax, o));
  __shared__ float smax[4];
  int wid = tid >> 6, lane = tid & 63;
  if (lane == 0) smax[wid] = mymax;
  __syncthreads();
  float m = fmaxf(fmaxf(smax[0], smax[1]), fmaxf(smax[2], smax[3]));

  float z = 0.0f, pm[8] = {};
#pragma unroll
  for (int t = 0; t < 4; t++) {
    int j = tid + t * 256;
    float e = __expf(loc[t] - m);
    z += e;
    const float* wr = wsim + j * 8;
#pragma unroll
    for (int d = 0; d < 8; d++) pm[d] = fmaf(e, wr[d], pm[d]);
  }
#pragma unroll
  for (int o = 32; o > 0; o >>= 1) {
    z += __shfl_down(z, o);
#pragma unroll
    for (int d = 0; d < 8; d++) pm[d] += __shfl_down(pm[d], o);
  }
  __shared__ float sred[4][9];
  if (lane == 0) {
    sred[wid][0] = z;
#pragma unroll
    for (int d = 0; d < 8; d++) sred[wid][1 + d] = pm[d];
  }
  __syncthreads();
  if (tid < 8) {
    float zt = sred[0][0] + sred[1][0] + sred[2][0] + sred[3][0];
    float pt = sred[0][1 + tid] + sred[1][1 + tid] + sred[2][1 + tid] + sred[3][1 + tid];
    M[i * 8 + tid] = pt / zt;
  }
}

// L5: gather64 (blocks 0..4999) | E (5000..5031)
__global__ __launch_bounds__(256) void mega5(const int* __restrict__ start,
                                             const int* __restrict__ ideg,
                                             const int* __restrict__ csr,
                                             const float* __restrict__ hraw,
                                             const float* __restrict__ dinv,
                                             const float* __restrict__ b1,
                                             float* __restrict__ hout,
                                             const float* __restrict__ emb,
                                             const float* __restrict__ M,
                                             float* __restrict__ E) {
  int b = blockIdx.x;
  if (b < 5000) {
    int lane = threadIdx.x & 63;
    int n = b * 4 + (threadIdx.x >> 6);
    int s0 = start[n], cnt = ideg[n];
    float acc = 0.0f;
    int k = 0;
    for (; k + 1 < cnt; k += 2) {
      int sA = csr[s0 + k], sB = csr[s0 + k + 1];
      float dA = dinv[sA], dB = dinv[sB];
      float vA = hraw[(size_t)sA * 64 + lane];
      float vB = hraw[(size_t)sB * 64 + lane];
      acc = fmaf(vA, dA, acc);
      acc = fmaf(vB, dB, acc);
    }
    if (k < cnt) {
      int sA = csr[s0 + k];
      acc = fmaf(hraw[(size_t)sA * 64 + lane], dinv[sA], acc);
    }
    float dn = dinv[n];
    float v = fmaf(acc, dn, hraw[(size_t)n * 64 + lane] * dn * dn) + b1[lane];
    hout[(size_t)n * 64 + lane] = fmaxf(v, 0.0f);
    return;
  }
  // ---- E(128x8) = emb(128x1024) @ M(1024x8), M from L2 ----
  int lane = threadIdx.x & 63;
  int r = (b - 5000) * 4 + (threadIdx.x >> 6);
  const float* er = emb + (size_t)r * 1024;
  float acc[8] = {};
  for (int it = 0; it < 16; it++) {
    int k = lane + it * 64;
    float e = er[k];
    const float4* mp = (const float4*)&M[k * 8];
    float4 m0 = mp[0], m1 = mp[1];
    acc[0] = fmaf(e, m0.x, acc[0]); acc[1] = fmaf(e, m0.y, acc[1]);
    acc[2] = fmaf(e, m0.z, acc[2]); acc[3] = fmaf(e, m0.w, acc[3]);
    acc[4] = fmaf(e, m1.x, acc[4]); acc[5] = fmaf(e, m1.y, acc[5]);
    acc[6] = fmaf(e, m1.z, acc[6]); acc[7] = fmaf(e, m1.w, acc[7]);
  }
#pragma unroll
  for (int o = 32; o > 0; o >>= 1)
#pragma unroll
    for (int d = 0; d < 8; d++) acc[d] += __shfl_down(acc[d], o);
  if (lane == 0)
#pragma unroll
    for (int d = 0; d < 8; d++) E[r * 8 + d] = acc[d];
}

// L6: xw2 (blocks 0..624) | semb (625..703)
__global__ __launch_bounds__(256) void mega6(const float* __restrict__ h1,
                                             const float* __restrict__ W2,
                                             float* __restrict__ h2raw,
                                             const float* __restrict__ x,
                                             const float* __restrict__ E,
                                             float* __restrict__ semb) {
  __shared__ __align__(16) char smem[8192];
  int b = blockIdx.x;
  if (b < 625) { xw_body<64, 32>(smem, h1, W2, h2raw, b); return; }
  // ---- semb = renorm(x @ E) ----
  float* El = (float*)smem;
  for (int t = threadIdx.x; t < 256; t += 256)
    ((float4*)El)[t] = ((const float4*)E)[t];
  __syncthreads();
  int row = (b - 625) * 256 + threadIdx.x;
  if (row >= NN) return;
  const float4* xr4 = (const float4*)(x + (size_t)row * 128);
  float s[8] = {};
#pragma unroll 4
  for (int k4 = 0; k4 < 32; k4++) {
    float4 xv = xr4[k4];
    int kb = k4 * 4;
#pragma unroll
    for (int u = 0; u < 4; u++) {
      float xk = (u == 0) ? xv.x : (u == 1) ? xv.y : (u == 2) ? xv.z : xv.w;
      const float4* ep = (const float4*)&El[(kb + u) * 8];
      float4 e0 = ep[0], e1 = ep[1];
      s[0] = fmaf(xk, e0.x, s[0]); s[1] = fmaf(xk, e0.y, s[1]);
      s[2] = fmaf(xk, e0.z, s[2]); s[3] = fmaf(xk, e0.w, s[3]);
      s[4] = fmaf(xk, e1.x, s[4]); s[5] = fmaf(xk, e1.y, s[5]);
      s[6] = fmaf(xk, e1.z, s[6]); s[7] = fmaf(xk, e1.w, s[7]);
    }
  }
  float n2 = 0.0f;
#pragma unroll
  for (int d = 0; d < 8; d++) n2 += s[d] * s[d];
  float n = sqrtf(n2);
  float sc = (n > 1.0f) ? 1.0f / (n + 1e-7f) : 1.0f;
#pragma unroll
  for (int d = 0; d < 8; d++) semb[(size_t)row * 8 + d] = s[d] * sc;
}

// L7: gather32 + fused renorm
__global__ __launch_bounds__(256) void mega7(const int* __restrict__ start,
                                             const int* __restrict__ ideg,
                                             const int* __restrict__ csr,
                                             const float* __restrict__ hraw,
                                             const float* __restrict__ dinv,
                                             const float* __restrict__ b2,
                                             float* __restrict__ g) {
  int lane = threadIdx.x & 31;
  int n = blockIdx.x * 8 + (threadIdx.x >> 5);
  int s0 = start[n], cnt = ideg[n];
  float acc = 0.0f;
  int k = 0;
  for (; k + 1 < cnt; k += 2) {
    int sA = csr[s0 + k], sB = csr[s0 + k + 1];
    float dA = dinv[sA], dB = dinv[sB];
    float vA = hraw[(size_t)sA * 32 + lane];
    float vB = hraw[(size_t)sB * 32 + lane];
    acc = fmaf(vA, dA, acc);
    acc = fmaf(vB, dB, acc);
  }
  if (k < cnt) {
    int sA = csr[s0 + k];
    acc = fmaf(hraw[(size_t)sA * 32 + lane], dinv[sA], acc);
  }
  float dn = dinv[n];
  float v = fmaf(acc, dn, hraw[(size_t)n * 32 + lane] * dn * dn) + b2[lane];
  v = fmaxf(v, 0.0f);
  float n2 = v * v;
#pragma unroll
  for (int o = 16; o > 0; o >>= 1) n2 += __shfl_xor(n2, o);
  float nrm = sqrtf(n2);
  float sc = (nrm > 1.0f) ? 1.0f / (nrm + 1e-7f) : 1.0f;
  g[(size_t)n * 32 + lane] = v * sc;
}

// L8: query head
__global__ __launch_bounds__(256) void mega8(const int* __restrict__ te,
                                             const float* __restrict__ g,
                                             const float* __restrict__ semb,
                                             const float* __restrict__ W1,
                                             const float* __restrict__ b1,
                                             const float* __restrict__ lw,
                                             const float* __restrict__ lb,
                                             float* __restrict__ out) {
  int q = blockIdx.x * 256 + threadIdx.x;
  if (q >= NQ) return;
  const int2 p = ((const int2*)te)[q];
  int i0 = p.x, i1 = p.y;
  float feat[40];
  const float4* g0 = (const float4*)(g + (size_t)i0 * 32);
  const float4* g1 = (const float4*)(g + (size_t)i1 * 32);
#pragma unroll
  for (int t = 0; t < 8; t++) {
    float4 a = g0[t], b = g1[t];
    float d0 = a.x - b.x, d1 = a.y - b.y, d2 = a.z - b.z, d3 = a.w - b.w;
    feat[t * 4 + 0] = d0 * d0; feat[t * 4 + 1] = d1 * d1;
    feat[t * 4 + 2] = d2 * d2; feat[t * 4 + 3] = d3 * d3;
  }
  const float4* s0 = (const float4*)(semb + (size_t)i0 * 8);
  const float4* s1 = (const float4*)(semb + (size_t)i1 * 8);
#pragma unroll
  for (int t = 0; t < 2; t++) {
    float4 a = s0[t], b = s1[t];
    float d0 = a.x - b.x, d1 = a.y - b.y, d2 = a.z - b.z, d3 = a.w - b.w;
    feat[32 + t * 4 + 0] = 0.1f * d0 * d0; feat[32 + t * 4 + 1] = 0.1f * d1 * d1;
    feat[32 + t * 4 + 2] = 0.1f * d2 * d2; feat[32 + t * 4 + 3] = 0.1f * d3 * d3;
  }
  float acc[32];
#pragma unroll
  for (int c = 0; c < 32; c++) acc[c] = b1[c];
#pragma unroll
  for (int k = 0; k < 40; k++) {
    float f = feat[k];
#pragma unroll
    for (int c = 0; c < 32; c++) acc[c] = fmaf(f, W1[k * 32 + c], acc[c]);
  }
  float accv = lb[0];
#pragma unroll
  for (int c = 0; c < 32; c++) {
    float a = acc[c];
    a = (a > 0.0f) ? a : 0.2f * a;
    accv = fmaf(a, lw[c], accv);
  }
  float sq = fminf(fabsf(accv), 40.0f);
  out[q] = 1.0f / (1.0f + __expf(sq - 2.0f));
}

extern "C" void kernel_launch(void* const* d_in, const int* in_sizes, int n_in,
                              void* d_out, int out_size, void* d_ws, size_t ws_size,
                              hipStream_t stream) {
  const float* x     = (const float*)d_in[0];
  const float* L0    = (const float*)d_in[1];
  const float* L1    = (const float*)d_in[2];
  const int*   ei    = (const int*)d_in[3];
  const int*   te    = (const int*)d_in[4];
  const float* W1    = (const float*)d_in[5];
  const float* b1    = (const float*)d_in[6];
  const float* W2    = (const float*)d_in[7];
  const float* b2    = (const float*)d_in[8];
  const float* wsim  = (const float*)d_in[9];
  const float* embs  = (const float*)d_in[10];
  const float* wod   = (const float*)d_in[11];
  const float* wL0   = (const float*)d_in[12];
  const float* wL1   = (const float*)d_in[13];
  const float* lin1W = (const float*)d_in[14];
  const float* lin1b = (const float*)d_in[15];
  const float* linW  = (const float*)d_in[16];
  const float* linb  = (const float*)d_in[17];
  float* out = (float*)d_out;

  int*   ideg   = (int*)d_ws;             // 20000
  int*   start  = ideg + 20000;           // 20000
  int*   cursor = start + 20000;          // 20000
  int*   csr    = cursor + 20000;         // 320000
  float* dinv   = (float*)(csr + 320000); // 20000
  float* h1raw  = dinv + 20000;           // 1,280,000
  float* h1     = h1raw + 1280000;        // 1,280,000
  float* h2raw  = h1raw;                  // alias: h1raw dead after gather64
  float* g      = h1 + 1280000;           // 640,000
  float* L0r    = g + 640000;             // 262,144
  float* L1r    = L0r + 262144;           // 262,144
  float* Ab     = L1r + 262144;           // 16,384
  float* Bb     = Ab + 16384;             // 16,384
  float* Ab2    = Bb + 16384;             // 16,384
  float* Mm     = Ab2 + 16384;            // 8,192
  float* Ee     = Mm + 8192;              // 1,024
  float* semb   = Ee + 1024;              // 160,000

  mega1<<<1457, 256, 0, stream>>>(L0, L1, L0r, L1r, x, W1, h1raw, ideg);
  mega2<<<1282, 256, 0, stream>>>(L0r, L1r, wL0, wL1, Ab, Bb, ei, ideg);
  mega3<<<17,   256, 0, stream>>>(wod, Ab, Ab2, ideg, start, cursor, dinv);
  mega4<<<2274, 256, 0, stream>>>(L0r, L1r, Ab2, Bb, wsim, Mm, ei, cursor, csr);
  mega5<<<5032, 256, 0, stream>>>(start, ideg, csr, h1raw, dinv, b1, h1, embs, Mm, Ee);
  mega6<<<704,  256, 0, stream>>>(h1, W2, h2raw, x, Ee, semb);
  mega7<<<2500, 256, 0, stream>>>(start, ideg, csr, h2raw, dinv, b2, g);
  mega8<<<782,  256, 0, stream>>>(te, g, semb, lin1W, lin1b, linW, linb, out);
}

// Round 4
// 186.402 us; speedup vs baseline: 2.0292x; 1.2195x over previous
//
#include <hip/hip_runtime.h>
#include <math.h>

#define NE 320000
#define NN 20000
#define NQ 200000

// ================= bodies =================

// ---- 512x512x512 f32 GEMM (C = A@A), 64x64 tile, 4x4 microtile ----
__device__ __forceinline__ void gemm512_body(char* smem, const float* __restrict__ A,
                                             float* __restrict__ C, int bb) {
  float (*As)[68] = (float(*)[68])smem;                 // 16 x 68
  float (*Bs)[68] = (float(*)[68])(smem + 16 * 68 * 4); // 16 x 68
  int tid = threadIdx.x;
  int tx = tid & 15, ty = tid >> 4;
  int brow = (bb >> 3) * 64;
  int bcol = (bb & 7) * 64;
  float c[4][4] = {};
  for (int k0 = 0; k0 < 512; k0 += 16) {
#pragma unroll
    for (int t = 0; t < 4; t++) {
      int idx = tid * 4 + t;
      int r = idx >> 4, cc = idx & 15;
      As[cc][r] = A[(size_t)(brow + r) * 512 + k0 + cc];
      int r2 = idx >> 6, c2 = idx & 63;
      Bs[r2][c2] = A[(size_t)(k0 + r2) * 512 + bcol + c2];
    }
    __syncthreads();
#pragma unroll
    for (int k = 0; k < 16; k++) {
      float a0 = As[k][ty * 4 + 0], a1 = As[k][ty * 4 + 1];
      float a2 = As[k][ty * 4 + 2], a3 = As[k][ty * 4 + 3];
      float b0 = Bs[k][tx * 4 + 0], b1 = Bs[k][tx * 4 + 1];
      float b2 = Bs[k][tx * 4 + 2], b3 = Bs[k][tx * 4 + 3];
      c[0][0] = fmaf(a0, b0, c[0][0]); c[0][1] = fmaf(a0, b1, c[0][1]);
      c[0][2] = fmaf(a0, b2, c[0][2]); c[0][3] = fmaf(a0, b3, c[0][3]);
      c[1][0] = fmaf(a1, b0, c[1][0]); c[1][1] = fmaf(a1, b1, c[1][1]);
      c[1][2] = fmaf(a1, b2, c[1][2]); c[1][3] = fmaf(a1, b3, c[1][3]);
      c[2][0] = fmaf(a2, b0, c[2][0]); c[2][1] = fmaf(a2, b1, c[2][1]);
      c[2][2] = fmaf(a2, b2, c[2][2]); c[2][3] = fmaf(a2, b3, c[2][3]);
      c[3][0] = fmaf(a3, b0, c[3][0]); c[3][1] = fmaf(a3, b1, c[3][1]);
      c[3][2] = fmaf(a3, b2, c[3][2]); c[3][3] = fmaf(a3, b3, c[3][3]);
    }
    __syncthreads();
  }
#pragma unroll
  for (int i = 0; i < 4; i++)
#pragma unroll
    for (int j = 0; j < 4; j++)
      C[(size_t)(brow + ty * 4 + i) * 512 + bcol + tx * 4 + j] = c[i][j];
}

// ---- skinny GEMM body: Y(MxN)=X(MxK)@W(KxN), W staged in LDS ----
template<int K, int N>
__device__ __forceinline__ void xw_body(char* smem, const float* __restrict__ X,
                                        const float* __restrict__ W,
                                        float* __restrict__ Y, int bb) {
  constexpr int TPR = N / 4;
  constexpr int ROWS = 256 / TPR;
  float* Wl = (float*)smem;
  for (int t = threadIdx.x; t < K * N / 4; t += 256)
    ((float4*)Wl)[t] = ((const float4*)W)[t];
  __syncthreads();
  int r = bb * ROWS + threadIdx.x / TPR;
  int c4 = (threadIdx.x % TPR) * 4;
  if (r >= NN) return;
  const float4* xr4 = (const float4*)(X + (size_t)r * K);
  float a0 = 0, a1 = 0, a2 = 0, a3 = 0;
#pragma unroll 4
  for (int k4 = 0; k4 < K / 4; k4++) {
    float4 xv = xr4[k4];
    int kb = k4 * 4;
    { const float4 w = *(const float4*)&Wl[(kb + 0) * N + c4];
      a0 = fmaf(xv.x, w.x, a0); a1 = fmaf(xv.x, w.y, a1); a2 = fmaf(xv.x, w.z, a2); a3 = fmaf(xv.x, w.w, a3); }
    { const float4 w = *(const float4*)&Wl[(kb + 1) * N + c4];
      a0 = fmaf(xv.y, w.x, a0); a1 = fmaf(xv.y, w.y, a1); a2 = fmaf(xv.y, w.z, a2); a3 = fmaf(xv.y, w.w, a3); }
    { const float4 w = *(const float4*)&Wl[(kb + 2) * N + c4];
      a0 = fmaf(xv.z, w.x, a0); a1 = fmaf(xv.z, w.y, a1); a2 = fmaf(xv.z, w.z, a2); a3 = fmaf(xv.z, w.w, a3); }
    { const float4 w = *(const float4*)&Wl[(kb + 3) * N + c4];
      a0 = fmaf(xv.w, w.x, a0); a1 = fmaf(xv.w, w.y, a1); a2 = fmaf(xv.w, w.z, a2); a3 = fmaf(xv.w, w.w, a3); }
  }
  float4 o; o.x = a0; o.y = a1; o.z = a2; o.w = a3;
  *(float4*)&Y[(size_t)r * N + c4] = o;
}

// ---- Ab-style body: Y(512x32) = X(512x512)@W(512x32), W streamed ----
__device__ __forceinline__ void sk512_body(const float* X, const float* W, float* Y, int b) {
  int r = b * 32 + threadIdx.x / 8;
  int c4 = (threadIdx.x % 8) * 4;
  const float4* xr4 = (const float4*)(X + (size_t)r * 512);
  float a0 = 0, a1 = 0, a2 = 0, a3 = 0;
#pragma unroll 2
  for (int k4 = 0; k4 < 128; k4++) {
    float4 xv = xr4[k4];
    int kb = k4 * 4;
    { const float4 w = *(const float4*)&W[(kb + 0) * 32 + c4];
      a0 = fmaf(xv.x, w.x, a0); a1 = fmaf(xv.x, w.y, a1); a2 = fmaf(xv.x, w.z, a2); a3 = fmaf(xv.x, w.w, a3); }
    { const float4 w = *(const float4*)&W[(kb + 1) * 32 + c4];
      a0 = fmaf(xv.y, w.x, a0); a1 = fmaf(xv.y, w.y, a1); a2 = fmaf(xv.y, w.z, a2); a3 = fmaf(xv.y, w.w, a3); }
    { const float4 w = *(const float4*)&W[(kb + 2) * 32 + c4];
      a0 = fmaf(xv.z, w.x, a0); a1 = fmaf(xv.z, w.y, a1); a2 = fmaf(xv.z, w.z, a2); a3 = fmaf(xv.z, w.w, a3); }
    { const float4 w = *(const float4*)&W[(kb + 3) * 32 + c4];
      a0 = fmaf(xv.w, w.x, a0); a1 = fmaf(xv.w, w.y, a1); a2 = fmaf(xv.w, w.z, a2); a3 = fmaf(xv.w, w.w, a3); }
  }
  float4 o; o.x = a0; o.y = a1; o.z = a2; o.w = a3;
  *(float4*)&Y[(size_t)r * 32 + c4] = o;
}

// ================= MEGA kernels =================

// L1: gemm512 x2 (blocks 0..127) | xw1 (128..1377) | zero ideg (1378..1456)
__global__ __launch_bounds__(256) void mega1(const float* __restrict__ L0,
                                             const float* __restrict__ L1,
                                             float* __restrict__ L0r,
                                             float* __restrict__ L1r,
                                             const float* __restrict__ x,
                                             const float* __restrict__ W1,
                                             float* __restrict__ h1raw,
                                             int* __restrict__ ideg) {
  __shared__ __align__(16) char smem[32768];
  int b = blockIdx.x;
  if (b < 128) {
    const float* A = (b < 64) ? L0 : L1;
    float* C = (b < 64) ? L0r : L1r;
    gemm512_body(smem, A, C, b & 63);
  } else if (b < 1378) {
    xw_body<128, 64>(smem, x, W1, h1raw, b - 128);
  } else {
    int i = (b - 1378) * 256 + threadIdx.x;
    if (i < NN) ideg[i] = 0;
  }
}

// L2: ab (blocks 0..31) | hist (32..1281)
__global__ __launch_bounds__(256) void mega2(const float* __restrict__ L0r,
                                             const float* __restrict__ L1r,
                                             const float* __restrict__ wL0,
                                             const float* __restrict__ wL1,
                                             float* __restrict__ Ab,
                                             float* __restrict__ Bb,
                                             const int* __restrict__ ei,
                                             int* __restrict__ ideg) {
  int b = blockIdx.x;
  if (b < 16) sk512_body(L0r, wL0, Ab, b);
  else if (b < 32) sk512_body(L1r, wL1, Bb, b - 16);
  else {
    int e = (b - 32) * 256 + threadIdx.x;
    if (e < NE) atomicAdd(&ideg[ei[NE + e]], 1);
  }
}

// L3: ab2 (blocks 0..15) | scan (block 16, fully-pipelined int4 version)
__global__ __launch_bounds__(256) void mega3(const float* __restrict__ wod,
                                             const float* __restrict__ Ab,
                                             float* __restrict__ Ab2,
                                             const int* __restrict__ ideg,
                                             int* __restrict__ start,
                                             int* __restrict__ cursor,
                                             float* __restrict__ dinv) {
  int b = blockIdx.x;
  if (b < 16) { sk512_body(wod, Ab, Ab2, b); return; }
  // ---- exclusive scan over 20000 degrees: 256 thr x 80 contiguous ints ----
  // 250*80 == 20000 exactly: threads 0..249 fully in range, 250..255 idle.
  __shared__ int wsum[4];
  int t = threadIdx.x;
  int base = t * 80;
  int4 c[20];
  const int4* ip = (const int4*)ideg + t * 20;
#pragma unroll
  for (int i = 0; i < 20; i++) c[i] = ip[i];  // all 20 loads in flight
  int s = 0;
  if (base < NN) {
#pragma unroll
    for (int i = 0; i < 20; i++) s += c[i].x + c[i].y + c[i].z + c[i].w;
  }
  int lane = t & 63, wid = t >> 6;
  int v = s;
#pragma unroll
  for (int o = 1; o < 64; o <<= 1) { int u = __shfl_up(v, o); if (lane >= o) v += u; }
  if (lane == 63) wsum[wid] = v;
  __syncthreads();
  int wbase = 0;
  for (int w = 0; w < wid; w++) wbase += wsum[w];
  int off = wbase + v - s;  // exclusive prefix for this thread's 80 elems
  if (base < NN) {
#pragma unroll
    for (int i = 0; i < 20; i++) {
      int4 cc = c[i];
      int4 st;
      st.x = off; off += cc.x;
      st.y = off; off += cc.y;
      st.z = off; off += cc.z;
      st.w = off; off += cc.w;
      ((int4*)start)[t * 20 + i] = st;
      ((int4*)cursor)[t * 20 + i] = st;
      float4 dv;
      dv.x = rsqrtf((float)(cc.x + 1));
      dv.y = rsqrtf((float)(cc.y + 1));
      dv.z = rsqrtf((float)(cc.z + 1));
      dv.w = rsqrtf((float)(cc.w + 1));
      ((float4*)dinv)[t * 20 + i] = dv;
    }
  }
}

// L4: softmaxM with fused rel_ (blocks 0..1023) | scatter (1024..2273)
__global__ __launch_bounds__(256) void mega4(const float* __restrict__ L0r,
                                             const float* __restrict__ L1r,
                                             const float* __restrict__ Ab2,
                                             const float* __restrict__ Bb,
                                             const float* __restrict__ wsim,
                                             float* __restrict__ M,
                                             const int* __restrict__ ei,
                                             int* __restrict__ cursor,
                                             int* __restrict__ csr) {
  int b = blockIdx.x;
  if (b >= 1024) {
    int e = (b - 1024) * 256 + threadIdx.x;
    if (e < NE) {
      int d = ei[NE + e];
      int pos = atomicAdd(&cursor[d], 1);
      csr[pos] = ei[e];
    }
    return;
  }
  int i = b;
  int tid = threadIdx.x;
  float urow[32];
  {
    const float4* up = (const float4*)((i < 512) ? (Ab2 + i * 32) : (Bb + (i - 512) * 32));
#pragma unroll
    for (int q = 0; q < 8; q++) {
      float4 u4 = up[q];
      urow[q * 4 + 0] = u4.x; urow[q * 4 + 1] = u4.y;
      urow[q * 4 + 2] = u4.z; urow[q * 4 + 3] = u4.w;
    }
  }
  float loc[4];
  float mymax = 0.0f;  // post-relu >= 0
#pragma unroll
  for (int t = 0; t < 4; t++) {
    int j = tid + t * 256;
    float v;
    if (i < 512) {
      if (j < 512) v = L0r[i * 512 + j];
      else {
        const float4* bj = (const float4*)(Bb + (j - 512) * 32);
        float acc = 0.0f;
#pragma unroll
        for (int q = 0; q < 8; q++) {
          float4 b4 = bj[q];
          acc = fmaf(urow[q * 4 + 0], b4.x, acc); acc = fmaf(urow[q * 4 + 1], b4.y, acc);
          acc = fmaf(urow[q * 4 + 2], b4.z, acc); acc = fmaf(urow[q * 4 + 3], b4.w, acc);
        }
        v = acc;
      }
    } else {
      int r = i - 512;
      if (j < 512) {
        const float4* aj = (const float4*)(Ab2 + j * 32);
        float acc = 0.0f;
#pragma unroll
        for (int q = 0; q < 8; q++) {
          float4 a4 = aj[q];
          acc = fmaf(urow[q * 4 + 0], a4.x, acc); acc = fmaf(urow[q * 4 + 1], a4.y, acc);
          acc = fmaf(urow[q * 4 + 2], a4.z, acc); acc = fmaf(urow[q * 4 + 3], a4.w, acc);
        }
        v = acc;
      } else v = L1r[r * 512 + (j - 512)];
    }
    v = fmaxf(v, 0.0f);
    loc[t] = v;
    mymax = fmaxf(mymax, v);
  }
#pragma unroll
  for (int o = 32; o > 0; o >>= 1) mymax = fmaxf(mymax, __shfl_down(mymax, o));
  __shared__ float smax[4];
  int wid = tid >> 6, lane = tid & 63;
  if (lane == 0) smax[wid] = mymax;
  __syncthreads();
  float m = fmaxf(fmaxf(smax[0], smax[1]), fmaxf(smax[2], smax[3]));

  float z = 0.0f, pm[8] = {};
#pragma unroll
  for (int t = 0; t < 4; t++) {
    int j = tid + t * 256;
    float e = __expf(loc[t] - m);
    z += e;
    const float* wr = wsim + j * 8;
#pragma unroll
    for (int d = 0; d < 8; d++) pm[d] = fmaf(e, wr[d], pm[d]);
  }
#pragma unroll
  for (int o = 32; o > 0; o >>= 1) {
    z += __shfl_down(z, o);
#pragma unroll
    for (int d = 0; d < 8; d++) pm[d] += __shfl_down(pm[d], o);
  }
  __shared__ float sred[4][9];
  if (lane == 0) {
    sred[wid][0] = z;
#pragma unroll
    for (int d = 0; d < 8; d++) sred[wid][1 + d] = pm[d];
  }
  __syncthreads();
  if (tid < 8) {
    float zt = sred[0][0] + sred[1][0] + sred[2][0] + sred[3][0];
    float pt = sred[0][1 + tid] + sred[1][1 + tid] + sred[2][1 + tid] + sred[3][1 + tid];
    M[i * 8 + tid] = pt / zt;
  }
}

// L5: gather64 (blocks 0..4999) | E (5000..5031)
__global__ __launch_bounds__(256) void mega5(const int* __restrict__ start,
                                             const int* __restrict__ ideg,
                                             const int* __restrict__ csr,
                                             const float* __restrict__ hraw,
                                             const float* __restrict__ dinv,
                                             const float* __restrict__ b1,
                                             float* __restrict__ hout,
                                             const float* __restrict__ emb,
                                             const float* __restrict__ M,
                                             float* __restrict__ E) {
  int b = blockIdx.x;
  if (b < 5000) {
    int lane = threadIdx.x & 63;
    int n = b * 4 + (threadIdx.x >> 6);
    int s0 = start[n], cnt = ideg[n];
    float acc = 0.0f;
    int k = 0;
    for (; k + 1 < cnt; k += 2) {
      int sA = csr[s0 + k], sB = csr[s0 + k + 1];
      float dA = dinv[sA], dB = dinv[sB];
      float vA = hraw[(size_t)sA * 64 + lane];
      float vB = hraw[(size_t)sB * 64 + lane];
      acc = fmaf(vA, dA, acc);
      acc = fmaf(vB, dB, acc);
    }
    if (k < cnt) {
      int sA = csr[s0 + k];
      acc = fmaf(hraw[(size_t)sA * 64 + lane], dinv[sA], acc);
    }
    float dn = dinv[n];
    float v = fmaf(acc, dn, hraw[(size_t)n * 64 + lane] * dn * dn) + b1[lane];
    hout[(size_t)n * 64 + lane] = fmaxf(v, 0.0f);
    return;
  }
  // ---- E(128x8) = emb(128x1024) @ M(1024x8), M from L2 ----
  int lane = threadIdx.x & 63;
  int r = (b - 5000) * 4 + (threadIdx.x >> 6);
  const float* er = emb + (size_t)r * 1024;
  float acc[8] = {};
  for (int it = 0; it < 16; it++) {
    int k = lane + it * 64;
    float e = er[k];
    const float4* mp = (const float4*)&M[k * 8];
    float4 m0 = mp[0], m1 = mp[1];
    acc[0] = fmaf(e, m0.x, acc[0]); acc[1] = fmaf(e, m0.y, acc[1]);
    acc[2] = fmaf(e, m0.z, acc[2]); acc[3] = fmaf(e, m0.w, acc[3]);
    acc[4] = fmaf(e, m1.x, acc[4]); acc[5] = fmaf(e, m1.y, acc[5]);
    acc[6] = fmaf(e, m1.z, acc[6]); acc[7] = fmaf(e, m1.w, acc[7]);
  }
#pragma unroll
  for (int o = 32; o > 0; o >>= 1)
#pragma unroll
    for (int d = 0; d < 8; d++) acc[d] += __shfl_down(acc[d], o);
  if (lane == 0)
#pragma unroll
    for (int d = 0; d < 8; d++) E[r * 8 + d] = acc[d];
}

// L6: xw2 (blocks 0..624) | semb (625..703)
__global__ __launch_bounds__(256) void mega6(const float* __restrict__ h1,
                                             const float* __restrict__ W2,
                                             float* __restrict__ h2raw,
                                             const float* __restrict__ x,
                                             const float* __restrict__ E,
                                             float* __restrict__ semb) {
  __shared__ __align__(16) char smem[8192];
  int b = blockIdx.x;
  if (b < 625) { xw_body<64, 32>(smem, h1, W2, h2raw, b); return; }
  // ---- semb = renorm(x @ E) ----
  float* El = (float*)smem;
  for (int t = threadIdx.x; t < 256; t += 256)
    ((float4*)El)[t] = ((const float4*)E)[t];
  __syncthreads();
  int row = (b - 625) * 256 + threadIdx.x;
  if (row >= NN) return;
  const float4* xr4 = (const float4*)(x + (size_t)row * 128);
  float s[8] = {};
#pragma unroll 4
  for (int k4 = 0; k4 < 32; k4++) {
    float4 xv = xr4[k4];
    int kb = k4 * 4;
#pragma unroll
    for (int u = 0; u < 4; u++) {
      float xk = (u == 0) ? xv.x : (u == 1) ? xv.y : (u == 2) ? xv.z : xv.w;
      const float4* ep = (const float4*)&El[(kb + u) * 8];
      float4 e0 = ep[0], e1 = ep[1];
      s[0] = fmaf(xk, e0.x, s[0]); s[1] = fmaf(xk, e0.y, s[1]);
      s[2] = fmaf(xk, e0.z, s[2]); s[3] = fmaf(xk, e0.w, s[3]);
      s[4] = fmaf(xk, e1.x, s[4]); s[5] = fmaf(xk, e1.y, s[5]);
      s[6] = fmaf(xk, e1.z, s[6]); s[7] = fmaf(xk, e1.w, s[7]);
    }
  }
  float n2 = 0.0f;
#pragma unroll
  for (int d = 0; d < 8; d++) n2 += s[d] * s[d];
  float n = sqrtf(n2);
  float sc = (n > 1.0f) ? 1.0f / (n + 1e-7f) : 1.0f;
#pragma unroll
  for (int d = 0; d < 8; d++) semb[(size_t)row * 8 + d] = s[d] * sc;
}

// L7: gather32 + fused renorm
__global__ __launch_bounds__(256) void mega7(const int* __restrict__ start,
                                             const int* __restrict__ ideg,
                                             const int* __restrict__ csr,
                                             const float* __restrict__ hraw,
                                             const float* __restrict__ dinv,
                                             const float* __restrict__ b2,
                                             float* __restrict__ g) {
  int lane = threadIdx.x & 31;
  int n = blockIdx.x * 8 + (threadIdx.x >> 5);
  int s0 = start[n], cnt = ideg[n];
  float acc = 0.0f;
  int k = 0;
  for (; k + 1 < cnt; k += 2) {
    int sA = csr[s0 + k], sB = csr[s0 + k + 1];
    float dA = dinv[sA], dB = dinv[sB];
    float vA = hraw[(size_t)sA * 32 + lane];
    float vB = hraw[(size_t)sB * 32 + lane];
    acc = fmaf(vA, dA, acc);
    acc = fmaf(vB, dB, acc);
  }
  if (k < cnt) {
    int sA = csr[s0 + k];
    acc = fmaf(hraw[(size_t)sA * 32 + lane], dinv[sA], acc);
  }
  float dn = dinv[n];
  float v = fmaf(acc, dn, hraw[(size_t)n * 32 + lane] * dn * dn) + b2[lane];
  v = fmaxf(v, 0.0f);
  float n2 = v * v;
#pragma unroll
  for (int o = 16; o > 0; o >>= 1) n2 += __shfl_xor(n2, o);
  float nrm = sqrtf(n2);
  float sc = (nrm > 1.0f) ? 1.0f / (nrm + 1e-7f) : 1.0f;
  g[(size_t)n * 32 + lane] = v * sc;
}

// L8: query head
__global__ __launch_bounds__(256) void mega8(const int* __restrict__ te,
                                             const float* __restrict__ g,
                                             const float* __restrict__ semb,
                                             const float* __restrict__ W1,
                                             const float* __restrict__ b1,
                                             const float* __restrict__ lw,
                                             const float* __restrict__ lb,
                                             float* __restrict__ out) {
  int q = blockIdx.x * 256 + threadIdx.x;
  if (q >= NQ) return;
  const int2 p = ((const int2*)te)[q];
  int i0 = p.x, i1 = p.y;
  float feat[40];
  const float4* g0 = (const float4*)(g + (size_t)i0 * 32);
  const float4* g1 = (const float4*)(g + (size_t)i1 * 32);
#pragma unroll
  for (int t = 0; t < 8; t++) {
    float4 a = g0[t], b = g1[t];
    float d0 = a.x - b.x, d1 = a.y - b.y, d2 = a.z - b.z, d3 = a.w - b.w;
    feat[t * 4 + 0] = d0 * d0; feat[t * 4 + 1] = d1 * d1;
    feat[t * 4 + 2] = d2 * d2; feat[t * 4 + 3] = d3 * d3;
  }
  const float4* s0 = (const float4*)(semb + (size_t)i0 * 8);
  const float4* s1 = (const float4*)(semb + (size_t)i1 * 8);
#pragma unroll
  for (int t = 0; t < 2; t++) {
    float4 a = s0[t], b = s1[t];
    float d0 = a.x - b.x, d1 = a.y - b.y, d2 = a.z - b.z, d3 = a.w - b.w;
    feat[32 + t * 4 + 0] = 0.1f * d0 * d0; feat[32 + t * 4 + 1] = 0.1f * d1 * d1;
    feat[32 + t * 4 + 2] = 0.1f * d2 * d2; feat[32 + t * 4 + 3] = 0.1f * d3 * d3;
  }
  float acc[32];
#pragma unroll
  for (int c = 0; c < 32; c++) acc[c] = b1[c];
#pragma unroll
  for (int k = 0; k < 40; k++) {
    float f = feat[k];
#pragma unroll
    for (int c = 0; c < 32; c++) acc[c] = fmaf(f, W1[k * 32 + c], acc[c]);
  }
  float accv = lb[0];
#pragma unroll
  for (int c = 0; c < 32; c++) {
    float a = acc[c];
    a = (a > 0.0f) ? a : 0.2f * a;
    accv = fmaf(a, lw[c], accv);
  }
  float sq = fminf(fabsf(accv), 40.0f);
  out[q] = 1.0f / (1.0f + __expf(sq - 2.0f));
}

extern "C" void kernel_launch(void* const* d_in, const int* in_sizes, int n_in,
                              void* d_out, int out_size, void* d_ws, size_t ws_size,
                              hipStream_t stream) {
  const float* x     = (const float*)d_in[0];
  const float* L0    = (const float*)d_in[1];
  const float* L1    = (const float*)d_in[2];
  const int*   ei    = (const int*)d_in[3];
  const int*   te    = (const int*)d_in[4];
  const float* W1    = (const float*)d_in[5];
  const float* b1    = (const float*)d_in[6];
  const float* W2    = (const float*)d_in[7];
  const float* b2    = (const float*)d_in[8];
  const float* wsim  = (const float*)d_in[9];
  const float* embs  = (const float*)d_in[10];
  const float* wod   = (const float*)d_in[11];
  const float* wL0   = (const float*)d_in[12];
  const float* wL1   = (const float*)d_in[13];
  const float* lin1W = (const float*)d_in[14];
  const float* lin1b = (const float*)d_in[15];
  const float* linW  = (const float*)d_in[16];
  const float* linb  = (const float*)d_in[17];
  float* out = (float*)d_out;

  int*   ideg   = (int*)d_ws;             // 20000
  int*   start  = ideg + 20000;           // 20000
  int*   cursor = start + 20000;          // 20000
  int*   csr    = cursor + 20000;         // 320000
  float* dinv   = (float*)(csr + 320000); // 20000
  float* h1raw  = dinv + 20000;           // 1,280,000
  float* h1     = h1raw + 1280000;        // 1,280,000
  float* h2raw  = h1raw;                  // alias: h1raw dead after gather64
  float* g      = h1 + 1280000;           // 640,000
  float* L0r    = g + 640000;             // 262,144
  float* L1r    = L0r + 262144;           // 262,144
  float* Ab     = L1r + 262144;           // 16,384
  float* Bb     = Ab + 16384;             // 16,384
  float* Ab2    = Bb + 16384;             // 16,384
  float* Mm     = Ab2 + 16384;            // 8,192
  float* Ee     = Mm + 8192;              // 1,024
  float* semb   = Ee + 1024;              // 160,000

  mega1<<<1457, 256, 0, stream>>>(L0, L1, L0r, L1r, x, W1, h1raw, ideg);
  mega2<<<1282, 256, 0, stream>>>(L0r, L1r, wL0, wL1, Ab, Bb, ei, ideg);
  mega3<<<17,   256, 0, stream>>>(wod, Ab, Ab2, ideg, start, cursor, dinv);
  mega4<<<2274, 256, 0, stream>>>(L0r, L1r, Ab2, Bb, wsim, Mm, ei, cursor, csr);
  mega5<<<5032, 256, 0, stream>>>(start, ideg, csr, h1raw, dinv, b1, h1, embs, Mm, Ee);
  mega6<<<704,  256, 0, stream>>>(h1, W2, h2raw, x, Ee, semb);
  mega7<<<2500, 256, 0, stream>>>(start, ideg, csr, h2raw, dinv, b2, g);
  mega8<<<782,  256, 0, stream>>>(te, g, semb, lin1W, lin1b, linW, linb, out);
}